// Round 6
// baseline (86.330 us; speedup 1.0000x reference)
//
#include <hip/hip_runtime.h>
#include <float.h>
#include <math.h>

#define B 128
#define D 128
#define N 3072      // 3*32*32
#define NBUCK 1024  // value buckets (uniform [0,1) -> ~3 elems/bucket)
#define TROW 64     // row-tiles (2 rows each)
#define NTILE (TROW*(TROW+1)/2)   // 2080 upper-tri 2x2 tiles
#define GRID 256
#define NTHREADS 512

// Cross-XCD data movement WITHOUT cache maintenance: relaxed agent-scope
// atomic stores compile to coherent (sc-bit) stores that bypass the
// non-coherent per-XCD L2s; readers' first CACHED read of any such line
// happens only after the writer's flag -> no staleness, no wb/inv ever.
// (Validated R4/R5.)
__device__ __forceinline__ void st_agent_f2(float* p, float a, float b) {
    union { float f[2]; unsigned long long u; } t;
    t.f[0] = a; t.f[1] = b;
    __hip_atomic_store((unsigned long long*)p, t.u, __ATOMIC_RELAXED,
                       __HIP_MEMORY_SCOPE_AGENT);
}

// Monotonic per-row generation flags (device globals: zero at load, never
// reset; each flag incremented exactly once per launch -> generation n is
// globally consistent across iterations and rocprof replays). Validated R5.
__device__ unsigned g_srt[B];     // sorted row r stored & drained
__device__ unsigned g_zc[B];      // zcos row r stored & drained
__device__ unsigned g_outz;       // out[0]=0 drained

__device__ __forceinline__ unsigned ld_flag(const unsigned* p) {
    return __hip_atomic_load(p, __ATOMIC_RELAXED, __HIP_MEMORY_SCOPE_AGENT);
}

// ---------------------------------------------------------------------------
// Fused kernel, 256 blocks x 512 threads, point-to-point sync only.
// Blocks 0..127:   bucket-sort x row bid (value buckets + LDS scatter +
//                  per-bucket insertion sort) -> xs, flag g_srt[row].
// Blocks 128..255: zcos row (bid-128) (validated 8-lane-dot shape), flag
//                  g_zc[row]; block 128 zeroes out (flag g_outz).
// All blocks:      local inv_s + diag recompute (validated R5) -> maxv with
//                  no cross-block wait; then pair tiles with per-tile waits
//                  on {4 sort flags, 2 zcos-row flags}.
// ---------------------------------------------------------------------------
__global__ __launch_bounds__(NTHREADS, 4) void fused_kernel(const float* __restrict__ x,
                                                            const float* __restrict__ z,
                                                            float* __restrict__ xs,
                                                            float* __restrict__ zcos,
                                                            float* __restrict__ out) {
    __shared__ unsigned hist[NBUCK];
    __shared__ unsigned bbase[NBUCK];
    __shared__ unsigned wsum[8];
    __shared__ unsigned wpre[8];
    __shared__ float sorted[N];
    __shared__ float inv_s[B];
    __shared__ float diag[B];
    __shared__ float partial[8];
    __shared__ float s_maxv;
    __shared__ unsigned sgen;

    int tid = threadIdx.x;
    int bid = blockIdx.x;
    int lane = tid & 63;
    int wid = tid >> 6;

    if (bid < B) {
        // ================= sort path: bucket sort of row bid =============
        int row = bid;
        float v[6]; int bb[6];
        const float2* xr = (const float2*)(x + (size_t)row * N);
        #pragma unroll
        for (int k = 0; k < 3; k++) {
            float2 t = xr[tid + k * 512];
            v[2 * k] = t.x; v[2 * k + 1] = t.y;
        }
        #pragma unroll
        for (int k = 0; k < 6; k++) {
            int b = (int)(v[k] * 1024.0f);   // monotone in v
            bb[k] = b < 0 ? 0 : (b > NBUCK - 1 ? NBUCK - 1 : b);
        }
        hist[tid] = 0; hist[tid + 512] = 0;
        __syncthreads();
        #pragma unroll
        for (int k = 0; k < 6; k++) atomicAdd(&hist[bb[k]], 1u);
        __syncthreads();

        // exclusive scan over 1024 bucket counts (2 buckets/thread)
        unsigned c0 = hist[2 * tid], c1 = hist[2 * tid + 1];
        unsigned ps = c0 + c1;                     // pair sum
        #pragma unroll
        for (int o = 1; o < 64; o <<= 1) {         // wave inclusive scan
            unsigned t = __shfl_up(ps, o, 64);
            if (lane >= o) ps += t;
        }
        if (lane == 63) wsum[wid] = ps;
        __syncthreads();
        if (tid == 0) {
            unsigned acc = 0;
            #pragma unroll
            for (int i = 0; i < 8; i++) { wpre[i] = acc; acc += wsum[i]; }
        }
        __syncthreads();
        unsigned excl = ps - (c0 + c1) + wpre[wid];
        bbase[2 * tid] = excl;
        bbase[2 * tid + 1] = excl + c0;
        __syncthreads();

        // scatter (rank via atomicAdd; bbase[b] ends at bucket end)
        #pragma unroll
        for (int k = 0; k < 6; k++) {
            unsigned pos = atomicAdd(&bbase[bb[k]], 1u);
            sorted[pos] = v[k];
        }
        __syncthreads();

        // per-bucket insertion sort (1 thread per bucket, 2 buckets/thread)
        #pragma unroll
        for (int t = 0; t < 2; t++) {
            int b = tid + t * 512;
            int end = (int)bbase[b];
            int st  = end - (int)hist[b];
            for (int i = st + 1; i < end; i++) {
                float key = sorted[i];
                int j2 = i - 1;
                while (j2 >= st && sorted[j2] > key) {
                    sorted[j2 + 1] = sorted[j2];
                    j2--;
                }
                sorted[j2 + 1] = key;
            }
        }
        __syncthreads();

        // coalesced store of fully sorted row via agent (L2-bypass) stores
        float* dst = xs + (size_t)row * N;
        #pragma unroll
        for (int k = 0; k < 3; k++) {
            int i = tid + k * 512;
            st_agent_f2(dst + 2 * i, sorted[2 * i], sorted[2 * i + 1]);
        }
        asm volatile("s_waitcnt vmcnt(0)" ::: "memory");
        __syncthreads();
        if (tid == 0) {
            sgen = __hip_atomic_fetch_add(&g_srt[row], 1u, __ATOMIC_RELAXED,
                                          __HIP_MEMORY_SCOPE_AGENT) + 1u;
        }

        // inv_s (4 threads/row) — needed for local diag
        {
            int r2 = tid >> 2, seg = tid & 3;
            const float4* zr = (const float4*)(z + r2 * D + seg * 32);
            float s = 0.f;
            #pragma unroll
            for (int u = 0; u < 8; u++) {
                float4 vv = zr[u];
                s += vv.x * vv.x + vv.y * vv.y + vv.z * vv.z + vv.w * vv.w;
            }
            s += __shfl_down(s, 2, 4);
            s += __shfl_down(s, 1, 4);
            if (seg == 0) inv_s[r2] = 1.0f / fmaxf(sqrtf(s), 1e-12f);
        }
        __syncthreads();
    } else {
        // ================= zcos path: row r = bid - 128 ==================
        int r = bid - B;
        if (bid == B && tid == 0) {
            __hip_atomic_store(out, 0.f, __ATOMIC_RELAXED,
                               __HIP_MEMORY_SCOPE_AGENT);
            asm volatile("s_waitcnt vmcnt(0)" ::: "memory");
            __hip_atomic_fetch_add(&g_outz, 1u, __ATOMIC_RELAXED,
                                   __HIP_MEMORY_SCOPE_AGENT);
        }
        // inv_s (4 threads/row)
        {
            int r2 = tid >> 2, seg = tid & 3;
            const float4* zr = (const float4*)(z + r2 * D + seg * 32);
            float s = 0.f;
            #pragma unroll
            for (int u = 0; u < 8; u++) {
                float4 vv = zr[u];
                s += vv.x * vv.x + vv.y * vv.y + vv.z * vv.z + vv.w * vv.w;
            }
            s += __shfl_down(s, 2, 4);
            s += __shfl_down(s, 1, 4);
            if (seg == 0) inv_s[r2] = 1.0f / fmaxf(sqrtf(s), 1e-12f);
        }
        __syncthreads();

        // zcos row r: 128 entries, 8 threads/entry, 2 reps (validated shape)
        int e = tid >> 3, sg = tid & 7;
        #pragma unroll
        for (int rep = 0; rep < 2; rep++) {
            int j = e + rep * 64;
            const float4* zi = (const float4*)(z + r * D + sg * 16);
            const float4* zj = (const float4*)(z + j * D + sg * 16);
            float dot = 0.f;
            #pragma unroll
            for (int u = 0; u < 4; u++) {
                float4 a = zi[u], b = zj[u];
                dot += a.x * b.x + a.y * b.y + a.z * b.z + a.w * b.w;
            }
            dot += __shfl_down(dot, 4, 8);
            dot += __shfl_down(dot, 2, 8);
            dot += __shfl_down(dot, 1, 8);
            if (sg == 0) {
                __hip_atomic_store(&zcos[r * B + j], dot * inv_s[r] * inv_s[j],
                                   __ATOMIC_RELAXED, __HIP_MEMORY_SCOPE_AGENT);
            }
        }
        asm volatile("s_waitcnt vmcnt(0)" ::: "memory");
        __syncthreads();
        if (tid == 0) {
            sgen = __hip_atomic_fetch_add(&g_zc[r], 1u, __ATOMIC_RELAXED,
                                          __HIP_MEMORY_SCOPE_AGENT) + 1u;
        }
        __syncthreads();
    }

    unsigned gen = sgen;

    // ---------------- local diag recompute (same shape as zcos writer) ----
    {
        int e = tid >> 3, sg = tid & 7;
        #pragma unroll
        for (int rep = 0; rep < 2; rep++) {
            int er = e + rep * 64;
            const float4* zi = (const float4*)(z + er * D + sg * 16);
            const float4* zj = (const float4*)(z + er * D + sg * 16);
            float dot = 0.f;
            #pragma unroll
            for (int u = 0; u < 4; u++) {
                float4 a = zi[u], b = zj[u];
                dot += a.x * b.x + a.y * b.y + a.z * b.z + a.w * b.w;
            }
            dot += __shfl_down(dot, 4, 8);
            dot += __shfl_down(dot, 2, 8);
            dot += __shfl_down(dot, 1, 8);
            if (sg == 0) diag[er] = dot * inv_s[er] * inv_s[er];
        }
    }
    __syncthreads();
    if (tid < 64) {
        float vv = fmaxf(diag[tid], diag[tid + 64]);
        #pragma unroll
        for (int o = 32; o > 0; o >>= 1) vv = fmaxf(vv, __shfl_down(vv, o, 64));
        if (tid == 0) s_maxv = vv;
    }
    __syncthreads();
    float maxv = s_maxv;

    // ---------------- pair tiles (validated math + decode) ----------------
    {
        int w = wid;                       // wave 0..7
        float acc = 0.f;

        // 2048 primary tiles (one per wave) + 32 leftovers spread across 32
        // different blocks (wave 0 of every 8th block) for balance.
        int nT = (w == 0 && (bid & 7) == 0) ? 2 : 1;
        for (int pass = 0; pass < nT; ++pass) {
            int T = (pass == 0) ? (bid * 8 + w) : (2048 + (bid >> 3));

            // decode T -> (ti, tj), ti<=tj over TROW=64 (validated decode)
            float ff = (float)(2 * TROW + 1);
            int ti = (int)((ff - sqrtf(ff * ff - 8.0f * (float)T)) * 0.5f);
            if (ti < 0) ti = 0;
            if (ti > TROW - 1) ti = TROW - 1;
            while ((ti + 1) * TROW - ((ti + 1) * ti) / 2 <= T) ti++;
            while (ti * TROW - (ti * (ti - 1)) / 2 > T) ti--;
            int tj = ti + (T - (ti * TROW - (ti * (ti - 1)) / 2));

            int r0 = 2 * ti, r1 = r0 + 1;
            int c0 = 2 * tj, c1 = c0 + 1;

            // per-tile wait: sorted rows r0,r1,c0,c1 + zcos rows r0,r1
            if (lane == 0) {
                while (ld_flag(&g_srt[r0]) < gen) __builtin_amdgcn_s_sleep(1);
                while (ld_flag(&g_srt[r1]) < gen) __builtin_amdgcn_s_sleep(1);
                while (ld_flag(&g_srt[c0]) < gen) __builtin_amdgcn_s_sleep(1);
                while (ld_flag(&g_srt[c1]) < gen) __builtin_amdgcn_s_sleep(1);
                while (ld_flag(&g_zc[r0]) < gen) __builtin_amdgcn_s_sleep(1);
                while (ld_flag(&g_zc[r1]) < gen) __builtin_amdgcn_s_sleep(1);
            }
            asm volatile("" ::: "memory");   // no load hoisting above polls

            const float4* a0 = (const float4*)(xs + (size_t)r0 * N);
            const float4* a1 = (const float4*)(xs + (size_t)r1 * N);
            const float4* b0 = (const float4*)(xs + (size_t)c0 * N);
            const float4* b1 = (const float4*)(xs + (size_t)c1 * N);

            float s00 = 0.f, s01 = 0.f, s10 = 0.f, s11 = 0.f;
            #pragma unroll
            for (int u = 0; u < N / 4 / 64; u++) {          // 12 iterations
                int idx = lane + u * 64;
                float4 va0 = a0[idx], va1 = a1[idx];
                float4 vb0 = b0[idx], vb1 = b1[idx];
                s00 += fabsf(va0.x - vb0.x) + fabsf(va0.y - vb0.y)
                     + fabsf(va0.z - vb0.z) + fabsf(va0.w - vb0.w);
                s01 += fabsf(va0.x - vb1.x) + fabsf(va0.y - vb1.y)
                     + fabsf(va0.z - vb1.z) + fabsf(va0.w - vb1.w);
                s10 += fabsf(va1.x - vb0.x) + fabsf(va1.y - vb0.y)
                     + fabsf(va1.z - vb0.z) + fabsf(va1.w - vb0.w);
                s11 += fabsf(va1.x - vb1.x) + fabsf(va1.y - vb1.y)
                     + fabsf(va1.z - vb1.z) + fabsf(va1.w - vb1.w);
            }
            #pragma unroll
            for (int o = 32; o > 0; o >>= 1) {
                s00 += __shfl_down(s00, o, 64);
                s01 += __shfl_down(s01, o, 64);
                s10 += __shfl_down(s10, o, 64);
                s11 += __shfl_down(s11, o, 64);
            }
            if (lane == 0) {
                bool diagt = (ti == tj);
                float w00 = diagt ? 1.0f : 2.0f;
                float w01 = 2.0f;
                float w10 = diagt ? 0.0f : 2.0f;
                float w11 = diagt ? 1.0f : 2.0f;
                float inv_n = 1.0f / N;
                float d00 = s00 * inv_n - (maxv - zcos[r0 * B + c0]);
                float d01 = s01 * inv_n - (maxv - zcos[r0 * B + c1]);
                float d10 = s10 * inv_n - (maxv - zcos[r1 * B + c0]);
                float d11 = s11 * inv_n - (maxv - zcos[r1 * B + c1]);
                acc += w00 * d00 * d00 + w01 * d01 * d01
                     + w10 * d10 * d10 + w11 * d11 * d11;
            }
        }
        if (lane == 0) partial[wid] = acc;
        __syncthreads();
        if (tid == 0) {
            while (ld_flag(&g_outz) < gen) __builtin_amdgcn_s_sleep(1);
            float blk = partial[0] + partial[1] + partial[2] + partial[3]
                      + partial[4] + partial[5] + partial[6] + partial[7];
            atomicAdd(out, blk * (1.0f / (B * B)));
        }
    }
}

extern "C" void kernel_launch(void* const* d_in, const int* in_sizes, int n_in,
                              void* d_out, int out_size, void* d_ws, size_t ws_size,
                              hipStream_t stream) {
    const float* z = (const float*)d_in[0];   // [128,128]
    const float* x = (const float*)d_in[1];   // [128,3,32,32]
    float* out = (float*)d_out;               // [1]
    float* ws = (float*)d_ws;

    float* zcos = ws;                         // 16384 floats
    float* xs   = ws + 16384;                 // 393216 floats (sorted rows)

    fused_kernel<<<GRID, NTHREADS, 0, stream>>>(x, z, xs, zcos, out);
}

// Round 7
// 78.971 us; speedup vs baseline: 1.0932x; 1.0932x over previous
//
#include <hip/hip_runtime.h>
#include <float.h>
#include <math.h>

#define B 128
#define D 128
#define N 3072      // 3*32*32
#define NBUCK 1024  // value buckets (uniform [0,1) -> ~3 elems/bucket)
#define TROW 64     // row-tiles (2 rows each)
#define NTILE (TROW*(TROW+1)/2)   // 2080 upper-tri 2x2 tiles
#define NTHREADS 512

// ---------------------------------------------------------------------------
// K1: blocks 0..127 bucket-sort x row bid -> xs (validated R6 sort algorithm;
//     plain cached stores — cross-kernel visibility via the kernel boundary,
//     exactly like validated R0/R1). Blocks 128..255: zcos row (bid-128)
//     (validated 8-lane-dot shape); block 128 zeroes out.
// ---------------------------------------------------------------------------
__global__ __launch_bounds__(NTHREADS) void prep_kernel(const float* __restrict__ x,
                                                        const float* __restrict__ z,
                                                        float* __restrict__ xs,
                                                        float* __restrict__ zcos,
                                                        float* __restrict__ out) {
    __shared__ unsigned hist[NBUCK];
    __shared__ unsigned bbase[NBUCK];
    __shared__ unsigned wsum[8];
    __shared__ unsigned wpre[8];
    __shared__ float sorted[N];
    __shared__ float inv_s[B];

    int tid = threadIdx.x;
    int bid = blockIdx.x;
    int lane = tid & 63;
    int wid = tid >> 6;

    if (bid < B) {
        // ================= bucket sort of row bid (validated R6) =========
        int row = bid;
        float v[6]; int bb[6];
        const float2* xr = (const float2*)(x + (size_t)row * N);
        #pragma unroll
        for (int k = 0; k < 3; k++) {
            float2 t = xr[tid + k * 512];
            v[2 * k] = t.x; v[2 * k + 1] = t.y;
        }
        #pragma unroll
        for (int k = 0; k < 6; k++) {
            int b = (int)(v[k] * 1024.0f);   // monotone in v
            bb[k] = b < 0 ? 0 : (b > NBUCK - 1 ? NBUCK - 1 : b);
        }
        hist[tid] = 0; hist[tid + 512] = 0;
        __syncthreads();
        #pragma unroll
        for (int k = 0; k < 6; k++) atomicAdd(&hist[bb[k]], 1u);
        __syncthreads();

        // exclusive scan over 1024 bucket counts (2 buckets/thread)
        unsigned c0 = hist[2 * tid], c1 = hist[2 * tid + 1];
        unsigned ps = c0 + c1;                     // pair sum
        #pragma unroll
        for (int o = 1; o < 64; o <<= 1) {         // wave inclusive scan
            unsigned t = __shfl_up(ps, o, 64);
            if (lane >= o) ps += t;
        }
        if (lane == 63) wsum[wid] = ps;
        __syncthreads();
        if (tid == 0) {
            unsigned acc = 0;
            #pragma unroll
            for (int i = 0; i < 8; i++) { wpre[i] = acc; acc += wsum[i]; }
        }
        __syncthreads();
        unsigned excl = ps - (c0 + c1) + wpre[wid];
        bbase[2 * tid] = excl;
        bbase[2 * tid + 1] = excl + c0;
        __syncthreads();

        // scatter (rank via atomicAdd; bbase[b] ends at bucket end)
        #pragma unroll
        for (int k = 0; k < 6; k++) {
            unsigned pos = atomicAdd(&bbase[bb[k]], 1u);
            sorted[pos] = v[k];
        }
        __syncthreads();

        // per-bucket insertion sort (2 buckets/thread, avg ~3 elems each)
        #pragma unroll
        for (int t = 0; t < 2; t++) {
            int b = tid + t * 512;
            int end = (int)bbase[b];
            int st  = end - (int)hist[b];
            for (int i = st + 1; i < end; i++) {
                float key = sorted[i];
                int j2 = i - 1;
                while (j2 >= st && sorted[j2] > key) {
                    sorted[j2 + 1] = sorted[j2];
                    j2--;
                }
                sorted[j2 + 1] = key;
            }
        }
        __syncthreads();

        // coalesced plain stores (kernel boundary provides coherence)
        float4* dst = (float4*)(xs + (size_t)row * N);
        dst[tid] = ((const float4*)sorted)[tid];
        if (tid < 256) dst[tid + 512] = ((const float4*)sorted)[tid + 512];
    } else {
        // ================= zcos row r = bid - 128 (validated) ============
        int r = bid - B;
        if (bid == B && tid == 0) out[0] = 0.f;

        // all-row inverse norms (4 threads per row)
        {
            int r2 = tid >> 2, seg = tid & 3;
            const float4* zr = (const float4*)(z + r2 * D + seg * 32);
            float s = 0.f;
            #pragma unroll
            for (int u = 0; u < 8; u++) {
                float4 vv = zr[u];
                s += vv.x * vv.x + vv.y * vv.y + vv.z * vv.z + vv.w * vv.w;
            }
            s += __shfl_down(s, 2, 4);
            s += __shfl_down(s, 1, 4);
            if (seg == 0) inv_s[r2] = 1.0f / fmaxf(sqrtf(s), 1e-12f);
        }
        __syncthreads();

        // zcos row r: 128 entries, 8 threads/entry, 2 reps (validated shape)
        int e = tid >> 3, sg = tid & 7;
        #pragma unroll
        for (int rep = 0; rep < 2; rep++) {
            int j = e + rep * 64;
            const float4* zi = (const float4*)(z + r * D + sg * 16);
            const float4* zj = (const float4*)(z + j * D + sg * 16);
            float dot = 0.f;
            #pragma unroll
            for (int u = 0; u < 4; u++) {
                float4 a = zi[u], b = zj[u];
                dot += a.x * b.x + a.y * b.y + a.z * b.z + a.w * b.w;
            }
            dot += __shfl_down(dot, 4, 8);
            dot += __shfl_down(dot, 2, 8);
            dot += __shfl_down(dot, 1, 8);
            if (sg == 0) zcos[r * B + j] = dot * inv_s[r] * inv_s[j];
        }
    }
}

// ---------------------------------------------------------------------------
// K2: pair tiles (validated R0 math/decode). 256 blocks x 8 waves; maxv from
// zcos diagonal (validated R0); 2048 primary tiles + 32 leftovers spread
// across 32 different blocks; one atomicAdd per block.
// ---------------------------------------------------------------------------
__global__ __launch_bounds__(NTHREADS) void pair_kernel(const float* __restrict__ xs,
                                                        const float* __restrict__ zcos,
                                                        float* __restrict__ out) {
    __shared__ float mx[2];
    __shared__ float partial[8];
    int tid = threadIdx.x;
    int bid = blockIdx.x;
    int lane = tid & 63;
    int w = tid >> 6;

    // diagonal max of zcos (max attained on diagonal — validated R0)
    if (tid < B) {
        float v = zcos[tid * (B + 1)];
        #pragma unroll
        for (int o = 32; o > 0; o >>= 1) v = fmaxf(v, __shfl_down(v, o, 64));
        if ((tid & 63) == 0) mx[tid >> 6] = v;
    }
    __syncthreads();
    float maxv = fmaxf(mx[0], mx[1]);

    float acc = 0.f;
    int nT = (w == 0 && (bid & 7) == 0) ? 2 : 1;
    for (int pass = 0; pass < nT; ++pass) {
        int T = (pass == 0) ? (bid * 8 + w) : (2048 + (bid >> 3));

        // decode T -> (ti, tj), ti<=tj over TROW=64 (validated decode)
        float ff = (float)(2 * TROW + 1);
        int ti = (int)((ff - sqrtf(ff * ff - 8.0f * (float)T)) * 0.5f);
        if (ti < 0) ti = 0;
        if (ti > TROW - 1) ti = TROW - 1;
        while ((ti + 1) * TROW - ((ti + 1) * ti) / 2 <= T) ti++;
        while (ti * TROW - (ti * (ti - 1)) / 2 > T) ti--;
        int tj = ti + (T - (ti * TROW - (ti * (ti - 1)) / 2));

        int r0 = 2 * ti, r1 = r0 + 1;
        int c0 = 2 * tj, c1 = c0 + 1;

        const float4* a0 = (const float4*)(xs + (size_t)r0 * N);
        const float4* a1 = (const float4*)(xs + (size_t)r1 * N);
        const float4* b0 = (const float4*)(xs + (size_t)c0 * N);
        const float4* b1 = (const float4*)(xs + (size_t)c1 * N);

        float s00 = 0.f, s01 = 0.f, s10 = 0.f, s11 = 0.f;
        #pragma unroll
        for (int u = 0; u < N / 4 / 64; u++) {          // 12 iterations
            int idx = lane + u * 64;
            float4 va0 = a0[idx], va1 = a1[idx];
            float4 vb0 = b0[idx], vb1 = b1[idx];
            s00 += fabsf(va0.x - vb0.x) + fabsf(va0.y - vb0.y)
                 + fabsf(va0.z - vb0.z) + fabsf(va0.w - vb0.w);
            s01 += fabsf(va0.x - vb1.x) + fabsf(va0.y - vb1.y)
                 + fabsf(va0.z - vb1.z) + fabsf(va0.w - vb1.w);
            s10 += fabsf(va1.x - vb0.x) + fabsf(va1.y - vb0.y)
                 + fabsf(va1.z - vb0.z) + fabsf(va1.w - vb0.w);
            s11 += fabsf(va1.x - vb1.x) + fabsf(va1.y - vb1.y)
                 + fabsf(va1.z - vb1.z) + fabsf(va1.w - vb1.w);
        }
        #pragma unroll
        for (int o = 32; o > 0; o >>= 1) {
            s00 += __shfl_down(s00, o, 64);
            s01 += __shfl_down(s01, o, 64);
            s10 += __shfl_down(s10, o, 64);
            s11 += __shfl_down(s11, o, 64);
        }
        if (lane == 0) {
            bool diag = (ti == tj);
            float w00 = diag ? 1.0f : 2.0f;
            float w01 = 2.0f;
            float w10 = diag ? 0.0f : 2.0f;
            float w11 = diag ? 1.0f : 2.0f;
            float inv_n = 1.0f / N;
            float d00 = s00 * inv_n - (maxv - zcos[r0 * B + c0]);
            float d01 = s01 * inv_n - (maxv - zcos[r0 * B + c1]);
            float d10 = s10 * inv_n - (maxv - zcos[r1 * B + c0]);
            float d11 = s11 * inv_n - (maxv - zcos[r1 * B + c1]);
            acc += w00 * d00 * d00 + w01 * d01 * d01
                 + w10 * d10 * d10 + w11 * d11 * d11;
        }
    }
    if (lane == 0) partial[w] = acc;
    __syncthreads();
    if (tid == 0) {
        float blk = partial[0] + partial[1] + partial[2] + partial[3]
                  + partial[4] + partial[5] + partial[6] + partial[7];
        atomicAdd(out, blk * (1.0f / (B * B)));
    }
}

extern "C" void kernel_launch(void* const* d_in, const int* in_sizes, int n_in,
                              void* d_out, int out_size, void* d_ws, size_t ws_size,
                              hipStream_t stream) {
    const float* z = (const float*)d_in[0];   // [128,128]
    const float* x = (const float*)d_in[1];   // [128,3,32,32]
    float* out = (float*)d_out;               // [1]
    float* ws = (float*)d_ws;

    float* zcos = ws;                         // 16384 floats
    float* xs   = ws + 16384;                 // 393216 floats (sorted rows)

    prep_kernel<<<2 * B, NTHREADS, 0, stream>>>(x, z, xs, zcos, out);
    pair_kernel<<<2 * B, NTHREADS, 0, stream>>>(xs, zcos, out);
}